// Round 16
// baseline (276.906 us; speedup 1.0000x reference)
//
#include <hip/hip_runtime.h>
#include <math.h>

#define DDIM 4096
#define EDIM 64
#define NROWS 16384
#define TOPK_K 8
#define DIGIT_BIAS 0x00808080

typedef int   i32x4 __attribute__((ext_vector_type(4)));
typedef float f32x4 __attribute__((ext_vector_type(4)));

// signed-digit int8 decomposition: bytes of (v+BIAS)^BIAS are signed digits
// d_p with v = sum d_p * 256^p (exact for |v| < 2^31 - 2^23)
__device__ __forceinline__ int digits_rn(float f) {
  int v = __float2int_rn(f);
  return (v + DIGIT_BIAS) ^ DIGIT_BIAS;
}
__device__ __forceinline__ int digits_tz(float f) {
  int v = (int)f;                    // trunc cvt; verified R9-R15
  return (v + DIGIT_BIAS) ^ DIGIT_BIAS;
}

__device__ __forceinline__ unsigned perm_b32(unsigned a, unsigned b, unsigned sel) {
#if __has_builtin(__builtin_amdgcn_perm)
  return __builtin_amdgcn_perm(a, b, sel);
#else
  union { unsigned u[2]; unsigned char c[8]; } s; s.u[0] = b; s.u[1] = a;
  unsigned r = 0;
  for (int i = 0; i < 4; ++i) r |= (unsigned)s.c[(sel >> (8*i)) & 7] << (8*i);
  return r;
#endif
}

// convert 4 f32 (group g) -> byte-group g of 4 digit-plane regs (x * 2^25)
__device__ __forceinline__ void cvtg(const f32x4 v, i32x4 (&An)[4], int g) {
  unsigned f0 = (unsigned)digits_tz(v[0] * 33554432.0f);
  unsigned f1 = (unsigned)digits_tz(v[1] * 33554432.0f);
  unsigned f2 = (unsigned)digits_tz(v[2] * 33554432.0f);
  unsigned f3 = (unsigned)digits_tz(v[3] * 33554432.0f);
  unsigned zl01 = perm_b32(f1, f0, 0x05010400u);
  unsigned zh01 = perm_b32(f1, f0, 0x07030602u);
  unsigned zl23 = perm_b32(f3, f2, 0x05010400u);
  unsigned zh23 = perm_b32(f3, f2, 0x07030602u);
  An[0][g] = (int)perm_b32(zl23, zl01, 0x05040100u);
  An[1][g] = (int)perm_b32(zl23, zl01, 0x07060302u);
  An[2][g] = (int)perm_b32(zh23, zh01, 0x05040100u);
  An[3][g] = (int)perm_b32(zh23, zh01, 0x07060302u);
}

// 13 MFMAs into 5 weight-class accs, round-robin (verified exact R9-R15)
__device__ __forceinline__ void mfma13(const i32x4 (&a)[4], const i32x4 (&b)[4],
                                       i32x4 (&c)[5]) {
  c[0] = __builtin_amdgcn_mfma_i32_16x16x64_i8(a[3], b[3], c[0], 0, 0, 0);
  c[1] = __builtin_amdgcn_mfma_i32_16x16x64_i8(a[3], b[2], c[1], 0, 0, 0);
  c[2] = __builtin_amdgcn_mfma_i32_16x16x64_i8(a[3], b[1], c[2], 0, 0, 0);
  c[3] = __builtin_amdgcn_mfma_i32_16x16x64_i8(a[3], b[0], c[3], 0, 0, 0);
  c[4] = __builtin_amdgcn_mfma_i32_16x16x64_i8(a[2], b[0], c[4], 0, 0, 0);
  c[1] = __builtin_amdgcn_mfma_i32_16x16x64_i8(a[2], b[3], c[1], 0, 0, 0);
  c[2] = __builtin_amdgcn_mfma_i32_16x16x64_i8(a[2], b[2], c[2], 0, 0, 0);
  c[3] = __builtin_amdgcn_mfma_i32_16x16x64_i8(a[2], b[1], c[3], 0, 0, 0);
  c[4] = __builtin_amdgcn_mfma_i32_16x16x64_i8(a[1], b[1], c[4], 0, 0, 0);
  c[2] = __builtin_amdgcn_mfma_i32_16x16x64_i8(a[1], b[3], c[2], 0, 0, 0);
  c[3] = __builtin_amdgcn_mfma_i32_16x16x64_i8(a[1], b[2], c[3], 0, 0, 0);
  c[4] = __builtin_amdgcn_mfma_i32_16x16x64_i8(a[0], b[2], c[4], 0, 0, 0);
  c[3] = __builtin_amdgcn_mfma_i32_16x16x64_i8(a[0], b[3], c[3], 0, 0, 0);
}

// ---------------------------------------------------------------------------
// Wr [4096][64] f32 -> 4 int8 digit planes (w*2^36), fragment-major,
// 64-K-tile granular. (verified R4-R15: idx exact) — UNCHANGED
// ---------------------------------------------------------------------------
__global__ __launch_bounds__(256) void wr_convert(const float* __restrict__ Wr,
                                                  char* __restrict__ wl8) {
  int t = blockIdx.x * 256 + threadIdx.x;
  int e = t & 63, k16 = t >> 6;
  int kt64 = k16 >> 2, kgg = k16 & 3, nf = e >> 4, col = e & 15;
  int D[16];
  #pragma unroll
  for (int j = 0; j < 16; ++j)
    D[j] = digits_rn(Wr[(size_t)(k16 * 16 + j) * EDIM + e] * 68719476736.0f);
  #pragma unroll
  for (int pl = 0; pl < 4; ++pl) {
    unsigned wv[4];
    #pragma unroll
    for (int g = 0; g < 4; ++g)
      wv[g] = ((unsigned)((D[4*g+0] >> (8*pl)) & 255))
            | ((unsigned)((D[4*g+1] >> (8*pl)) & 255) << 8)
            | ((unsigned)((D[4*g+2] >> (8*pl)) & 255) << 16)
            | ((unsigned)((D[4*g+3] >> (8*pl)) & 255) << 24);
    i32x4 val = {(int)wv[0], (int)wv[1], (int)wv[2], (int)wv[3]};
    *(i32x4*)(wl8 + (size_t)pl * 262144 + (size_t)(kt64 * 4 + nf) * 1024
              + (size_t)(kgg * 16 + col) * 16) = val;
  }
}

// ---------------------------------------------------------------------------
// Pass 1 — MAX-TLP split-K. 2048 blocks (= 8 blocks/CU) x 256 threads,
// ZERO LDS, __launch_bounds__(256,8) -> VGPR<=64 fit -> 8 waves/SIMD.
// Per-wave serial chains are covered by 8-deep TLP instead of software
// pipelining. Block: 16 rows x (K-half via blockIdx.y); 4 nw-waves.
// Numerics byte-identical to verified R9 body. Partials: raw i32 classes.
// part[((ks*NROWS+row)*64+e)*8 + cls]
// ---------------------------------------------------------------------------
__global__ __launch_bounds__(256, 8) void router_pass1(
    const float* __restrict__ x, const char* __restrict__ wl8,
    int* __restrict__ part) {
  const int lane = threadIdx.x & 63;
  const int nw   = threadIdx.x >> 6;      // 0..3
  const int ks   = blockIdx.y;            // 0..1 K-half
  const int row0 = blockIdx.x * 16;
  const int kg   = lane >> 4;

  const char* xr = (const char*)x + (size_t)(row0 + (lane & 15)) * (DDIM * 4)
                   + (size_t)ks * 8192 + kg * 64;
  const char* wr = wl8 + (size_t)ks * 131072 + (size_t)nw * 1024 + (size_t)lane * 16;

  i32x4 acc[5] = {};
  i32x4 A[4];

  for (int t = 0; t < 32; ++t) {
    const char* xp = xr + (size_t)t * 256;
    f32x4 X[4];
    #pragma unroll
    for (int c = 0; c < 4; ++c) X[c] = *(const f32x4*)(xp + c * 16);
    const char* bp = wr + (size_t)t * 4096;
    i32x4 B[4];
    #pragma unroll
    for (int pl = 0; pl < 4; ++pl)
      B[pl] = *(const i32x4*)(bp + (size_t)pl * 262144);
    cvtg(X[0], A, 0); cvtg(X[1], A, 1); cvtg(X[2], A, 2); cvtg(X[3], A, 3);
    mfma13(A, B, acc);
  }

  // write class partials (exact i32), 32B aligned per (row,e)
  const int e = nw * 16 + (lane & 15);
  #pragma unroll
  for (int j = 0; j < 4; ++j) {
    int row = row0 + (lane >> 4) * 4 + j;      // C/D: row=(lane>>4)*4+reg
    int* p = part + ((size_t)(ks * NROWS + row) * 64 + e) * 8;
    i32x4 v = {acc[0][j], acc[1][j], acc[2][j], acc[3][j]};
    *(i32x4*)p = v;
    p[4] = acc[4][j];
  }
}

// ---------------------------------------------------------------------------
// Pass 2 — i64-exact ks-combine (bit-identical logits to verified single-K
// fp64 path), bias, top-8 (verified), sparse softmax. Wave per row.
// ---------------------------------------------------------------------------
__global__ __launch_bounds__(256) void router_pass2(
    const int* __restrict__ part, const float* __restrict__ br,
    float* __restrict__ out_scores, float* __restrict__ out_idx) {
  const int lane = threadIdx.x & 63;
  const int row  = blockIdx.x * 4 + (threadIdx.x >> 6);

  const int* p0 = part + ((size_t)row * 64 + lane) * 8;
  const int* p1 = part + ((size_t)(NROWS + row) * 64 + lane) * 8;
  i32x4 a = *(const i32x4*)p0;
  i32x4 b = *(const i32x4*)p1;
  int a4 = p0[4], b4 = p1[4];

  double v0 = (double)((long long)a[0] + b[0]) * 0x1p-13
            + (double)((long long)a[1] + b[1]) * 0x1p-21
            + (double)((long long)a[2] + b[2]) * 0x1p-29
            + (double)((long long)a[3] + b[3]) * 0x1p-37
            + (double)((long long)a4   + b4)   * 0x1p-45
            + (double)br[lane];

  double cur = v0;
  bool sel  = false;
  int myidx = 0;
  double maxv = 0.0;
  #pragma unroll
  for (int k = 0; k < TOPK_K; ++k) {
    double bv = cur;
    int    bi = lane;
    #pragma unroll
    for (int off = 32; off; off >>= 1) {
      double ov = __shfl_xor(bv, off);
      int    oi = __shfl_xor(bi, off);
      if (ov > bv || (ov == bv && oi < bi)) { bv = ov; bi = oi; }
    }
    if (k == 0) maxv = bv;
    if (lane == k) myidx = bi;
    if (lane == bi) { cur = -__builtin_inf(); sel = true; }
  }
  float pv = sel ? expf((float)(v0 - maxv)) : 0.f;
  float ssum = pv;
  #pragma unroll
  for (int off = 32; off; off >>= 1) ssum += __shfl_xor(ssum, off);

  out_scores[(size_t)row * 64 + lane] = pv / ssum;
  if (lane < TOPK_K) out_idx[(size_t)row * 8 + lane] = (float)myidx;
}

extern "C" void kernel_launch(void* const* d_in, const int* in_sizes, int n_in,
                              void* d_out, int out_size, void* d_ws, size_t ws_size,
                              hipStream_t stream) {
  const float* x  = (const float*)d_in[0];
  const float* Wr = (const float*)d_in[1];
  const float* br = (const float*)d_in[2];
  // d_in[3] (Wn), d_in[4] (bn): dead code in the reference — intentionally unused.

  char* wl8 = (char*)d_ws;                          // 1 MiB digit planes
  int*  part = (int*)(wl8 + (1 << 20));             // 2*16384*64*8*4 = 64 MiB
  float* out_scores = (float*)d_out;
  float* out_idx    = out_scores + (size_t)NROWS * EDIM;

  wr_convert<<<64, 256, 0, stream>>>(Wr, wl8);
  router_pass1<<<dim3(NROWS / 16, 2), 256, 0, stream>>>(x, wl8, part);
  router_pass2<<<NROWS / 4, 256, 0, stream>>>(part, br, out_scores, out_idx);
}

// Round 17
// 126.578 us; speedup vs baseline: 2.1876x; 2.1876x over previous
//
#include <hip/hip_runtime.h>
#include <math.h>

#define DDIM 4096
#define EDIM 64
#define NROWS 16384
#define MBLK 16
#define NKT 64            // K-tiles of 64
#define TOPK_K 8
#define DIGIT_BIAS 0x00808080

typedef int   i32x4 __attribute__((ext_vector_type(4)));
typedef float f32x4 __attribute__((ext_vector_type(4)));

// signed-digit int8 decomposition: bytes of (v+BIAS)^BIAS are signed digits
// d_p with v = sum d_p * 256^p (exact for |v| < 2^31 - 2^23)
__device__ __forceinline__ int digits_rn(float f) {
  int v = __float2int_rn(f);
  return (v + DIGIT_BIAS) ^ DIGIT_BIAS;
}
__device__ __forceinline__ int digits_tz(float f) {
  int v = (int)f;                    // trunc cvt; verified R9-R16
  return (v + DIGIT_BIAS) ^ DIGIT_BIAS;
}

__device__ __forceinline__ unsigned perm_b32(unsigned a, unsigned b, unsigned sel) {
#if __has_builtin(__builtin_amdgcn_perm)
  return __builtin_amdgcn_perm(a, b, sel);
#else
  union { unsigned u[2]; unsigned char c[8]; } s; s.u[0] = b; s.u[1] = a;
  unsigned r = 0;
  for (int i = 0; i < 4; ++i) r |= (unsigned)s.c[(sel >> (8*i)) & 7] << (8*i);
  return r;
#endif
}

// convert 4 f32 (group g) -> byte-group g of 4 digit-plane regs (x * 2^25)
__device__ __forceinline__ void cvtg(const f32x4 v, i32x4 (&An)[4], int g) {
  unsigned f0 = (unsigned)digits_tz(v[0] * 33554432.0f);
  unsigned f1 = (unsigned)digits_tz(v[1] * 33554432.0f);
  unsigned f2 = (unsigned)digits_tz(v[2] * 33554432.0f);
  unsigned f3 = (unsigned)digits_tz(v[3] * 33554432.0f);
  unsigned zl01 = perm_b32(f1, f0, 0x05010400u);
  unsigned zh01 = perm_b32(f1, f0, 0x07030602u);
  unsigned zl23 = perm_b32(f3, f2, 0x05010400u);
  unsigned zh23 = perm_b32(f3, f2, 0x07030602u);
  An[0][g] = (int)perm_b32(zl23, zl01, 0x05040100u);
  An[1][g] = (int)perm_b32(zl23, zl01, 0x07060302u);
  An[2][g] = (int)perm_b32(zh23, zh01, 0x05040100u);
  An[3][g] = (int)perm_b32(zh23, zh01, 0x07060302u);
}

// 13 MFMAs into 5 weight-class accs, round-robin (verified exact R9-R16)
__device__ __forceinline__ void mfma13(const i32x4 (&a)[4], const i32x4 (&b)[4],
                                       i32x4 (&c)[5]) {
  c[0] = __builtin_amdgcn_mfma_i32_16x16x64_i8(a[3], b[3], c[0], 0, 0, 0);
  c[1] = __builtin_amdgcn_mfma_i32_16x16x64_i8(a[3], b[2], c[1], 0, 0, 0);
  c[2] = __builtin_amdgcn_mfma_i32_16x16x64_i8(a[3], b[1], c[2], 0, 0, 0);
  c[3] = __builtin_amdgcn_mfma_i32_16x16x64_i8(a[3], b[0], c[3], 0, 0, 0);
  c[4] = __builtin_amdgcn_mfma_i32_16x16x64_i8(a[2], b[0], c[4], 0, 0, 0);
  c[1] = __builtin_amdgcn_mfma_i32_16x16x64_i8(a[2], b[3], c[1], 0, 0, 0);
  c[2] = __builtin_amdgcn_mfma_i32_16x16x64_i8(a[2], b[2], c[2], 0, 0, 0);
  c[3] = __builtin_amdgcn_mfma_i32_16x16x64_i8(a[2], b[1], c[3], 0, 0, 0);
  c[4] = __builtin_amdgcn_mfma_i32_16x16x64_i8(a[1], b[1], c[4], 0, 0, 0);
  c[2] = __builtin_amdgcn_mfma_i32_16x16x64_i8(a[1], b[3], c[2], 0, 0, 0);
  c[3] = __builtin_amdgcn_mfma_i32_16x16x64_i8(a[1], b[2], c[3], 0, 0, 0);
  c[4] = __builtin_amdgcn_mfma_i32_16x16x64_i8(a[0], b[2], c[4], 0, 0, 0);
  c[3] = __builtin_amdgcn_mfma_i32_16x16x64_i8(a[0], b[3], c[3], 0, 0, 0);
}

// ---------------------------------------------------------------------------
// Wr [4096][64] f32 -> 4 int8 digit planes (w*2^36), fragment-major,
// 64-K-tile granular. (verified R4-R16: idx exact) — UNCHANGED
// ---------------------------------------------------------------------------
__global__ __launch_bounds__(256) void wr_convert(const float* __restrict__ Wr,
                                                  char* __restrict__ wl8) {
  int t = blockIdx.x * 256 + threadIdx.x;
  int e = t & 63, k16 = t >> 6;
  int kt64 = k16 >> 2, kgg = k16 & 3, nf = e >> 4, col = e & 15;
  int D[16];
  #pragma unroll
  for (int j = 0; j < 16; ++j)
    D[j] = digits_rn(Wr[(size_t)(k16 * 16 + j) * EDIM + e] * 68719476736.0f);
  #pragma unroll
  for (int pl = 0; pl < 4; ++pl) {
    unsigned wv[4];
    #pragma unroll
    for (int g = 0; g < 4; ++g)
      wv[g] = ((unsigned)((D[4*g+0] >> (8*pl)) & 255))
            | ((unsigned)((D[4*g+1] >> (8*pl)) & 255) << 8)
            | ((unsigned)((D[4*g+2] >> (8*pl)) & 255) << 16)
            | ((unsigned)((D[4*g+3] >> (8*pl)) & 255) << 24);
    i32x4 val = {(int)wv[0], (int)wv[1], (int)wv[2], (int)wv[3]};
    *(i32x4*)(wl8 + (size_t)pl * 262144 + (size_t)(kt64 * 4 + nf) * 1024
              + (size_t)(kgg * 16 + col) * 16) = val;
  }
}

// ---------------------------------------------------------------------------
// Fused exact router — x staged COALESCED through LDS (R7-verified
// swizzled-source global_load_lds: kills the 64-line/instr scatter that
// front-end-bound R9/R13/R16), W read direct per-lane from L2 (R9-verified,
// coalesced). m97 single-barrier loop. MBLK=16, 256 threads (4 nw-waves),
// 1024 blocks = 4/CU for TLP. LDS 16 KiB.
// ---------------------------------------------------------------------------
__global__ __launch_bounds__(256, 4) void router_fused(
    const float* __restrict__ x, const char* __restrict__ wl8,
    const float* __restrict__ br,
    float* __restrict__ out_scores, float* __restrict__ out_idx) {
  __shared__ __align__(16) char xs[2][4096];   // x tile double-buffer
  __shared__ double ls[MBLK * EDIM];           // epilogue logits (8 KiB)

  const int tid  = threadIdx.x;
  const int lane = tid & 63;
  const int w    = tid >> 6;        // 0..3 = nw (16-expert band)
  const int kg   = lane >> 4;
  const int r_l  = lane & 15;
  const int row0 = blockIdx.x * MBLK;
  const float bias = br[w * 16 + r_l];

  // staging: wave w stages rows w*4..w*4+3; LDS linear = L[r][c] with the
  // source column XOR-swizzled (m173 pattern, verified R7)
  const int srow = w * 4 + kg;
  const int scol = lane & 15;
  const char* sxr = (const char*)x + (size_t)(row0 + srow) * (DDIM * 4)
                    + (size_t)((scol ^ (srow & 7)) << 4);
  char* sdst = &xs[0][0] + (w * 1024 + lane * 16);

  // W direct per-lane (R9-verified): contiguous 1 KiB per (nw, tile, plane)
  const char* wr = wl8 + (size_t)w * 1024 + (size_t)lane * 16;

  i32x4 acc[5] = {};   // digit-weight classes s6..s2

  auto stage = [&](int t, int b) {
    __builtin_amdgcn_global_load_lds(
        (const __attribute__((address_space(1))) unsigned int*)(const void*)
            (sxr + (size_t)t * 256),
        (__attribute__((address_space(3))) unsigned int*)(void*)(sdst + b * 4096),
        16, 0, 0);
  };

  auto compute = [&](int t, int b) {
    const char* bp = wr + (size_t)t * 4096;
    i32x4 B[4];
    #pragma unroll
    for (int pl = 0; pl < 4; ++pl)
      B[pl] = *(const i32x4*)(bp + (size_t)pl * 262144);
    const char* Xb = &xs[0][0] + b * 4096;
    f32x4 X[4];
    #pragma unroll
    for (int c = 0; c < 4; ++c) {
      int chunk = (kg * 4 + c) ^ (r_l & 7);
      X[c] = *(const f32x4*)(Xb + r_l * 256 + chunk * 16);
    }
    i32x4 A[4];
    cvtg(X[0], A, 0); cvtg(X[1], A, 1); cvtg(X[2], A, 2); cvtg(X[3], A, 3);
    mfma13(A, B, acc);
  };

  stage(0, 0);
  __syncthreads();
  for (int t = 0; t < NKT; ++t) {
    if (t + 1 < NKT) stage(t + 1, (t + 1) & 1);   // issued BEFORE compute (T3)
    compute(t, t & 1);
    __syncthreads();
  }

  // ---- epilogue: fp64 combine (class s: 2^(8s-61)), top-8, sparse softmax ----
  {
    int cc = w * 16 + r_l;
    #pragma unroll
    for (int j = 0; j < 4; ++j) {
      int r = kg * 4 + j;                      // C/D: row=(lane>>4)*4+reg
      ls[r * 64 + cc] = (double)acc[0][j] * 0x1p-13 + (double)acc[1][j] * 0x1p-21
                      + (double)acc[2][j] * 0x1p-29 + (double)acc[3][j] * 0x1p-37
                      + (double)acc[4][j] * 0x1p-45 + (double)bias;
    }
  }
  __syncthreads();

  for (int rr = 0; rr < 4; ++rr) {
    int r = w * 4 + rr;
    double v0 = ls[r * 64 + lane];
    double cur = v0;
    bool sel  = false;
    int myidx = 0;
    double maxv = 0.0;
    #pragma unroll
    for (int k = 0; k < TOPK_K; ++k) {
      double bv = cur;
      int    bi = lane;
      #pragma unroll
      for (int off = 32; off; off >>= 1) {
        double ov = __shfl_xor(bv, off);
        int    oi = __shfl_xor(bi, off);
        if (ov > bv || (ov == bv && oi < bi)) { bv = ov; bi = oi; }
      }
      if (k == 0) maxv = bv;
      if (lane == k) myidx = bi;
      if (lane == bi) { cur = -__builtin_inf(); sel = true; }
    }
    float pv = sel ? expf((float)(v0 - maxv)) : 0.f;
    float ssum = pv;
    #pragma unroll
    for (int off = 32; off; off >>= 1) ssum += __shfl_xor(ssum, off);

    size_t rg = (size_t)row0 + r;
    out_scores[rg * 64 + lane] = pv / ssum;
    if (lane < TOPK_K) out_idx[rg * 8 + lane] = (float)myidx;
  }
}

extern "C" void kernel_launch(void* const* d_in, const int* in_sizes, int n_in,
                              void* d_out, int out_size, void* d_ws, size_t ws_size,
                              hipStream_t stream) {
  const float* x  = (const float*)d_in[0];
  const float* Wr = (const float*)d_in[1];
  const float* br = (const float*)d_in[2];
  // d_in[3] (Wn), d_in[4] (bn): dead code in the reference — intentionally unused.

  char* wl8 = (char*)d_ws;                          // 4 planes x 256 KiB = 1 MiB
  float* out_scores = (float*)d_out;
  float* out_idx    = out_scores + (size_t)NROWS * EDIM;

  wr_convert<<<64, 256, 0, stream>>>(Wr, wl8);
  router_fused<<<NROWS / MBLK, 256, 0, stream>>>(x, wl8, br, out_scores, out_idx);
}